// Round 16
// baseline (57.018 us; speedup 1.0000x reference)
//
#include <hip/hip_runtime.h>
#include <math.h>

#define NB   4
#define SEQN 512
#define SEQM 512
#define QS   256   // Q_SIZE == K_SIZE
#define HH   128   // H
#define DV   256   // D_V
#define BM   (NB * SEQM)   // 2048 global k rows

static constexpr float kPreScale = 2.8853900817779268f;  // 2*log2(e)
static constexpr float kLog2e    = 1.4426950408889634f;

typedef float v2f __attribute__((ext_vector_type(2)));

#if __has_builtin(__builtin_amdgcn_exp2f)
__device__ __forceinline__ float fexp2(float x) { return __builtin_amdgcn_exp2f(x); }
#else
__device__ __forceinline__ float fexp2(float x) { return exp2f(x); }
#endif

#if __has_builtin(__builtin_amdgcn_rcpf)
__device__ __forceinline__ float frcp(float x) { return __builtin_amdgcn_rcpf(x); }
#else
__device__ __forceinline__ float frcp(float x) { return 1.0f / x; }
#endif

__device__ __forceinline__ v2f splat(float x) { v2f r; r.x = x; r.y = x; return r; }

// Fused q/k projection + tanh precompute (unchanged from R14/R15).
// grid: 512 blocks, 512 threads. Block: 8 rows x 128 cols; thread: 2 rows.
// Q output (row-major): qt[row][ A_0..A_127 | wv_0*A_0 .. wv_127*A_127 ]
// K output (transposed, PLAIN A): ktA[h][global_row] = A
__global__ __launch_bounds__(512) void proj_kernel(
    const float* __restrict__ query, const float* __restrict__ key,
    const float* __restrict__ Wq, const float* __restrict__ Wk,
    const float* __restrict__ wv,
    float* __restrict__ qt, float* __restrict__ ktA) {
  const int t = threadIdx.x;
  const int half = (NB * SEQN) / 8;            // 256
  const bool isK = blockIdx.x >= half;
  const int rb   = isK ? (blockIdx.x - half) : blockIdx.x;
  const float* __restrict__ in = isK ? key : query;
  const float* __restrict__ W  = isK ? Wk  : Wq;
  const int row0 = rb * 8;

  const int j  = t & 127;                                      // output column (h)
  const int r0 = __builtin_amdgcn_readfirstlane((t >> 7) * 2); // wave-uniform -> SGPR

  const float* __restrict__ x0p = in + (size_t)(row0 + r0 + 0) * QS;
  const float* __restrict__ x1p = in + (size_t)(row0 + r0 + 1) * QS;

  float a0 = 0.f, a1 = 0.f;
  for (int k0 = 0; k0 < QS; k0 += 4) {
    const float w0 = W[(k0 + 0) * HH + j];
    const float w1 = W[(k0 + 1) * HH + j];
    const float w2 = W[(k0 + 2) * HH + j];
    const float w3 = W[(k0 + 3) * HH + j];
    const float4 x0 = *reinterpret_cast<const float4*>(x0p + k0);  // s_load
    const float4 x1 = *reinterpret_cast<const float4*>(x1p + k0);
    a0 = fmaf(x0.x, w0, fmaf(x0.y, w1, fmaf(x0.z, w2, fmaf(x0.w, w3, a0))));
    a1 = fmaf(x1.x, w0, fmaf(x1.y, w1, fmaf(x1.z, w2, fmaf(x1.w, w3, a1))));
  }
  const float wvj = wv[j];
  float acc[2] = {a0, a1};
#pragma unroll
  for (int r = 0; r < 2; ++r) {
    const float e  = fexp2(acc[r] * kPreScale);          // e^{2x}
    const float rc = frcp(e + 1.0f);
    float A = fmaf(-2.0f, rc, 1.0f);                     // tanh(x)
    A = fminf(fmaxf(A, -0.99999988f), 0.99999988f);      // keep d = 1+AB > 0
    const int grow = row0 + r0 + r;
    if (isK) {
      ktA[(size_t)j * BM + grow] = A;                    // plain A, coalesced
    } else {
      qt[(size_t)grow * (2 * HH) + j]      = A;
      qt[(size_t)grow * (2 * HH) + HH + j] = wvj * A;
    }
  }
}

// Scores only — PACKED fp32 math (v_pk_*_f32), zero LDS, zero barriers.
// grid = 4b x 128 n-tiles(4 rows) x 2 m-halves = 1024 blocks, 256 threads
// (4 blocks/CU, 16 waves/CU, blocks drain independently).
// Thread: m-pair (packed in v2f halves) x 2 query rows -> 4 scores.
// score = sum_h wv_h*(A+B)/(1+AB) via pairwise rational tree, all ops packed.
__global__ __launch_bounds__(256) void scores_kernel(
    const float* __restrict__ qt, const float* __restrict__ ktA,
    const float* __restrict__ wv, float* __restrict__ sc) {
  const int t   = threadIdx.x;
  const int bid = blockIdx.x;
  const int mh  = bid & 1;              // m half (256 m's)
  const int nt  = (bid >> 1) & 127;     // 4-row tile
  const int b   = bid >> 8;
  const int n0  = nt * 4;
  const int m0  = mh * 256 + 2 * (t & 127);   // this thread's m pair
  // row-pair base 0 or 2 within the tile; wave-uniform (t>>7 const per wave)
  const int g2  = __builtin_amdgcn_readfirstlane((t >> 7) * 2);

  const float* __restrict__ qb = qt + ((size_t)b * SEQN + n0 + g2) * (2 * HH);
  const float* __restrict__ kb = ktA + (size_t)b * SEQM + m0;   // coalesced v2f

  v2f N0 = splat(0.f), N1 = splat(0.f);
  v2f D0 = splat(1.f), D1 = splat(1.f);
  const v2f one = splat(1.f);

  // k register double-buffer: prefetch chunk 0 ({A(m0),A(m1)} per h)
  v2f fb[8];
#pragma unroll
  for (int jj = 0; jj < 8; ++jj)
    fb[jj] = *reinterpret_cast<const v2f*>(kb + (size_t)jj * BM);

  for (int h0 = 0; h0 < HH; h0 += 8) {
    v2f kA[8];
#pragma unroll
    for (int jj = 0; jj < 8; ++jj) kA[jj] = fb[jj];
    if (h0 + 8 < HH) {
#pragma unroll
      for (int jj = 0; jj < 8; ++jj)
        fb[jj] = *reinterpret_cast<const v2f*>(kb + (size_t)(h0 + 8 + jj) * BM);
    }
    // u = wv_h * A_k (packed, shared across the 2 q rows)
    const float4 wva = *reinterpret_cast<const float4*>(wv + h0);      // s_load
    const float4 wvb = *reinterpret_cast<const float4*>(wv + h0 + 4);
    v2f u[8];
    u[0] = splat(wva.x) * kA[0]; u[1] = splat(wva.y) * kA[1];
    u[2] = splat(wva.z) * kA[2]; u[3] = splat(wva.w) * kA[3];
    u[4] = splat(wvb.x) * kA[4]; u[5] = splat(wvb.y) * kA[5];
    u[6] = splat(wvb.z) * kA[6]; u[7] = splat(wvb.w) * kA[7];
#pragma unroll
    for (int n = 0; n < 2; ++n) {
      const float* qr = qb + n * (2 * HH);
      const float4 qa0 = *reinterpret_cast<const float4*>(qr + h0);        // s_load
      const float4 qa1 = *reinterpret_cast<const float4*>(qr + h0 + 4);
      const float4 qv0 = *reinterpret_cast<const float4*>(qr + HH + h0);
      const float4 qv1 = *reinterpret_cast<const float4*>(qr + HH + h0 + 4);
      // s_i = wv*(A+B) = qv + u ; d_i = 1 + A*B   (all packed over the m pair)
      v2f s0 = splat(qv0.x) + u[0], d0 = splat(qa0.x) * kA[0] + one;
      v2f s1 = splat(qv0.y) + u[1], d1 = splat(qa0.y) * kA[1] + one;
      v2f s2 = splat(qv0.z) + u[2], d2 = splat(qa0.z) * kA[2] + one;
      v2f s3 = splat(qv0.w) + u[3], d3 = splat(qa0.w) * kA[3] + one;
      v2f s4 = splat(qv1.x) + u[4], d4 = splat(qa1.x) * kA[4] + one;
      v2f s5 = splat(qv1.y) + u[5], d5 = splat(qa1.y) * kA[5] + one;
      v2f s6 = splat(qv1.z) + u[6], d6 = splat(qa1.z) * kA[6] + one;
      v2f s7 = splat(qv1.w) + u[7], d7 = splat(qa1.w) * kA[7] + one;
      // pairwise rational tree (packed): sum s_i/d_i -> t07/e07
      v2f t01 = s0 * d1 + s1 * d0, e01 = d0 * d1;
      v2f t23 = s2 * d3 + s3 * d2, e23 = d2 * d3;
      v2f t45 = s4 * d5 + s5 * d4, e45 = d4 * d5;
      v2f t67 = s6 * d7 + s7 * d6, e67 = d6 * d7;
      v2f t03 = t01 * e23 + t23 * e01, e03 = e01 * e23;
      v2f t47 = t45 * e67 + t67 * e45, e47 = e45 * e67;
      v2f t07 = t03 * e47 + t47 * e03, e07 = e03 * e47;
      if (n == 0) { N0 = N0 * e07 + t07 * D0; D0 = D0 * e07; }
      else        { N1 = N1 * e07 + t07 * D1; D1 = D1 * e07; }
    }
  }
  {
    float* srow = sc + ((size_t)b * SEQN + n0 + g2) * SEQM + m0;
    float2 r0; r0.x = N0.x * frcp(D0.x); r0.y = N0.y * frcp(D0.y);
    float2 r1; r1.x = N1.x * frcp(D1.x); r1.y = N1.y * frcp(D1.y);
    *reinterpret_cast<float2*>(srow)        = r0;
    *reinterpret_cast<float2*>(srow + SEQM) = r1;
  }
}

// Softmax + PV (verbatim from R6, proven). grid = 256 blocks, 1024 threads.
// Waves 0..7: softmax of one full score row each (512 keys).
// PV: quarter q = t>>8 owns 128 m's; d = t&255; combine quarters via LDS.
__global__ __launch_bounds__(1024) void softpv_kernel(
    const float* __restrict__ sc, const float* __restrict__ value,
    float* __restrict__ out) {
  constexpr int TN = 8;
  __shared__ float sp[TN][SEQM];        // 16 KB: unnormalized p
  __shared__ float pvbuf[3][TN][DV];    // 24 KB: quarter partials
  __shared__ float rs[TN];

  const int t  = threadIdx.x;           // 0..1023
  const int b  = blockIdx.x / (SEQN / TN);
  const int n0 = (blockIdx.x % (SEQN / TN)) * TN;
  const int wave = t >> 6;
  const int lane = t & 63;

  if (wave < TN) {
    const float* __restrict__ srow = sc + ((size_t)b * SEQN + n0 + wave) * SEQM;
    float v[8];
    float mx = -1e30f;
#pragma unroll
    for (int i = 0; i < 8; ++i) {
      v[i] = srow[lane + 64 * i];
      mx = fmaxf(mx, v[i]);
    }
#pragma unroll
    for (int off = 32; off > 0; off >>= 1) mx = fmaxf(mx, __shfl_xor(mx, off));
    float sum = 0.f;
#pragma unroll
    for (int i = 0; i < 8; ++i) {
      const float p = fexp2((v[i] - mx) * kLog2e);
      sum += p;
      sp[wave][lane + 64 * i] = p;
    }
#pragma unroll
    for (int off = 32; off > 0; off >>= 1) sum += __shfl_xor(sum, off);
    if (lane == 0) rs[wave] = 1.0f / sum;
  }
  __syncthreads();

  const float* __restrict__ vb = value + (size_t)b * SEQM * DV;
  const int d = t & 255;
  const int q = t >> 8;                 // quarter 0..3
  float o[TN];
#pragma unroll
  for (int n = 0; n < TN; ++n) o[n] = 0.f;
  const int mbeg = q * 128;
  for (int m0 = mbeg; m0 < mbeg + 128; m0 += 4) {
    const float v0 = vb[(size_t)(m0 + 0) * DV + d];
    const float v1 = vb[(size_t)(m0 + 1) * DV + d];
    const float v2 = vb[(size_t)(m0 + 2) * DV + d];
    const float v3 = vb[(size_t)(m0 + 3) * DV + d];
#pragma unroll
    for (int n = 0; n < TN; ++n) {
      const float4 p4 = *reinterpret_cast<const float4*>(&sp[n][m0]);  // broadcast
      o[n] = fmaf(p4.x, v0, fmaf(p4.y, v1, fmaf(p4.z, v2, fmaf(p4.w, v3, o[n]))));
    }
  }
  if (q > 0) {
#pragma unroll
    for (int n = 0; n < TN; ++n) pvbuf[q - 1][n][d] = o[n];
  }
  __syncthreads();
  if (q == 0) {
    const size_t ob = ((size_t)b * SEQN + n0) * DV + (size_t)d;
#pragma unroll
    for (int n = 0; n < TN; ++n) {
      const float r = (o[n] + pvbuf[0][n][d] + pvbuf[1][n][d] + pvbuf[2][n][d]) * rs[n];
      out[ob + (size_t)n * DV] = r;
    }
  }
}

extern "C" void kernel_launch(void* const* d_in, const int* in_sizes, int n_in,
                              void* d_out, int out_size, void* d_ws, size_t ws_size,
                              hipStream_t stream) {
  const float* query = (const float*)d_in[0];   // (4,512,256)
  const float* key   = (const float*)d_in[1];   // (4,512,256)
  const float* value = (const float*)d_in[2];   // (4,512,256)
  const float* W_q   = (const float*)d_in[3];   // (256,128)
  const float* W_k   = (const float*)d_in[4];   // (256,128)
  const float* W_v   = (const float*)d_in[5];   // (128,)
  float* out = (float*)d_out;                   // (4,512,256) f32

  // qt parks in d_out (2 MB): scores_kernel finishes reading qt before
  // softpv_kernel (stream-ordered) overwrites d_out -> no hazard.
  float* qt  = (float*)d_out;                        // (2048, 256) [A | wv*A]
  float* ktA = (float*)d_ws;                         // (128, 2048) plain A, 1 MB
  float* sc  = ktA + (size_t)HH * BM;                // (4,512,512) raw scores, 4 MB

  proj_kernel<<<2 * (NB * SEQN) / 8, 512, 0, stream>>>(query, key, W_q, W_k, W_v, qt, ktA);
  scores_kernel<<<NB * 128 * 2, 256, 0, stream>>>(qt, ktA, W_v, sc);
  softpv_kernel<<<NB * (SEQN / 8), 1024, 0, stream>>>(sc, value, out);
}

// Round 17
// 46.265 us; speedup vs baseline: 1.2324x; 1.2324x over previous
//
#include <hip/hip_runtime.h>
#include <math.h>

#define NB   4
#define SEQN 512
#define SEQM 512
#define QS   256   // Q_SIZE == K_SIZE
#define HH   128   // H
#define DV   256   // D_V
#define BM   (NB * SEQM)   // 2048 global k rows

static constexpr float kPreScale = 2.8853900817779268f;  // 2*log2(e)
static constexpr float kLog2e    = 1.4426950408889634f;

#if __has_builtin(__builtin_amdgcn_exp2f)
__device__ __forceinline__ float fexp2(float x) { return __builtin_amdgcn_exp2f(x); }
#else
__device__ __forceinline__ float fexp2(float x) { return exp2f(x); }
#endif

#if __has_builtin(__builtin_amdgcn_rcpf)
__device__ __forceinline__ float frcp(float x) { return __builtin_amdgcn_rcpf(x); }
#else
__device__ __forceinline__ float frcp(float x) { return 1.0f / x; }
#endif

// Fused q/k projection + tanh precompute.
// grid: 512 blocks, 512 threads. Block: 8 rows x 128 cols; thread: 2 rows.
// Q output (row-major): qt[row][ A_0..A_127 | wv_0*A_0 .. wv_127*A_127 ]
// K output (CHUNK-TILED): ktT[c][global_row][j] = A for h = 8c+j.
//   R17: kills the 8 KB-stride h-walk of kt[h][m] (L2 channel aliasing —
//   the invariant behind the R7-R16 ~40us plateau). A thread's per-chunk
//   k-read is now 64 B contiguous; a wave reads 4 KB sequential.
__global__ __launch_bounds__(512) void proj_kernel(
    const float* __restrict__ query, const float* __restrict__ key,
    const float* __restrict__ Wq, const float* __restrict__ Wk,
    const float* __restrict__ wv,
    float* __restrict__ qt, float* __restrict__ ktT) {
  const int t = threadIdx.x;
  const int half = (NB * SEQN) / 8;            // 256
  const bool isK = blockIdx.x >= half;
  const int rb   = isK ? (blockIdx.x - half) : blockIdx.x;
  const float* __restrict__ in = isK ? key : query;
  const float* __restrict__ W  = isK ? Wk  : Wq;
  const int row0 = rb * 8;

  const int j  = t & 127;                                      // output column (h)
  const int r0 = __builtin_amdgcn_readfirstlane((t >> 7) * 2); // wave-uniform -> SGPR

  const float* __restrict__ x0p = in + (size_t)(row0 + r0 + 0) * QS;
  const float* __restrict__ x1p = in + (size_t)(row0 + r0 + 1) * QS;

  float a0 = 0.f, a1 = 0.f;
  for (int k0 = 0; k0 < QS; k0 += 4) {
    const float w0 = W[(k0 + 0) * HH + j];
    const float w1 = W[(k0 + 1) * HH + j];
    const float w2 = W[(k0 + 2) * HH + j];
    const float w3 = W[(k0 + 3) * HH + j];
    const float4 x0 = *reinterpret_cast<const float4*>(x0p + k0);  // s_load
    const float4 x1 = *reinterpret_cast<const float4*>(x1p + k0);
    a0 = fmaf(x0.x, w0, fmaf(x0.y, w1, fmaf(x0.z, w2, fmaf(x0.w, w3, a0))));
    a1 = fmaf(x1.x, w0, fmaf(x1.y, w1, fmaf(x1.z, w2, fmaf(x1.w, w3, a1))));
  }
  const float wvj = wv[j];
  float acc[2] = {a0, a1};
#pragma unroll
  for (int r = 0; r < 2; ++r) {
    const float e  = fexp2(acc[r] * kPreScale);          // e^{2x}
    const float rc = frcp(e + 1.0f);
    float A = fmaf(-2.0f, rc, 1.0f);                     // tanh(x)
    A = fminf(fmaxf(A, -0.99999988f), 0.99999988f);      // keep d = 1+AB > 0
    const int grow = row0 + r0 + r;
    if (isK) {
      // chunk-tiled: [c][grow][j2], c = j>>3, j2 = j&7
      ktT[(((size_t)(j >> 3) * BM) + grow) * 8 + (j & 7)] = A;
    } else {
      qt[(size_t)grow * (2 * HH) + j]      = A;
      qt[(size_t)grow * (2 * HH) + HH + j] = wvj * A;
    }
  }
}

// Fused scores + softmax + PV (R14 structure verbatim; only k layout/loads
// changed). grid = NB * (SEQN/8) = 256 blocks, 1024 threads, 48 KB LDS.
// Thread (g = t>>8: row-pair; mslot = t&255: m-pair) computes 4 scores.
__global__ __launch_bounds__(1024) void fused_kernel(
    const float* __restrict__ qt, const float* __restrict__ ktT,
    const float* __restrict__ wv, const float* __restrict__ value,
    float* __restrict__ out) {
  __shared__ float sp[8][SEQM];        // 16 KB: scores then unnormalized p
  __shared__ float pvbuf[4][8][DV];    // 32 KB: PV partial buffers
  __shared__ float rsh[8];             // 1/rowsum

  const int t  = threadIdx.x;            // 0..1023
  const int b  = blockIdx.x >> 6;        // 4 batches x 64 tiles
  const int n0 = (blockIdx.x & 63) * 8;
  const int mslot = t & 255;
  const int m0 = 2 * mslot;
  const int g2 = __builtin_amdgcn_readfirstlane((t >> 8) * 2);

  const float* __restrict__ qb = qt + ((size_t)b * SEQN + n0 + g2) * (2 * HH);
  // k base for this thread's m-pair: 64 B contiguous per chunk,
  // chunks advance by BM*8 floats (64 KB) -> streams across L2 channels.
  const float* __restrict__ kbase = ktT + ((size_t)b * SEQM + m0) * 8;

  float N00 = 0.f, N01 = 0.f, N10 = 0.f, N11 = 0.f;
  float D00 = 1.f, D01 = 1.f, D10 = 1.f, D11 = 1.f;

  // register double-buffer: prefetch chunk 0 (4 x dwordx4, contiguous)
  float4 f0, f1, f2, f3;
  f0 = *reinterpret_cast<const float4*>(kbase + 0);   // m0 h0-3
  f1 = *reinterpret_cast<const float4*>(kbase + 4);   // m0 h4-7
  f2 = *reinterpret_cast<const float4*>(kbase + 8);   // m1 h0-3
  f3 = *reinterpret_cast<const float4*>(kbase + 12);  // m1 h4-7

  for (int c = 0; c < 16; ++c) {
    const int h0 = c * 8;
    float bA0[8], bA1[8];
    bA0[0] = f0.x; bA0[1] = f0.y; bA0[2] = f0.z; bA0[3] = f0.w;
    bA0[4] = f1.x; bA0[5] = f1.y; bA0[6] = f1.z; bA0[7] = f1.w;
    bA1[0] = f2.x; bA1[1] = f2.y; bA1[2] = f2.z; bA1[3] = f2.w;
    bA1[4] = f3.x; bA1[5] = f3.y; bA1[6] = f3.z; bA1[7] = f3.w;
    if (c + 1 < 16) {
      const float* nb = kbase + (size_t)(c + 1) * BM * 8;
      f0 = *reinterpret_cast<const float4*>(nb + 0);
      f1 = *reinterpret_cast<const float4*>(nb + 4);
      f2 = *reinterpret_cast<const float4*>(nb + 8);
      f3 = *reinterpret_cast<const float4*>(nb + 12);
    }
    // wv chunk: wave-uniform -> s_loads
    const float4 wva = *reinterpret_cast<const float4*>(wv + h0);
    const float4 wvb = *reinterpret_cast<const float4*>(wv + h0 + 4);
    // u = wv * A_k, shared across the 2 q-rows
    float u0[8], u1[8];
    u0[0] = wva.x * bA0[0]; u1[0] = wva.x * bA1[0];
    u0[1] = wva.y * bA0[1]; u1[1] = wva.y * bA1[1];
    u0[2] = wva.z * bA0[2]; u1[2] = wva.z * bA1[2];
    u0[3] = wva.w * bA0[3]; u1[3] = wva.w * bA1[3];
    u0[4] = wvb.x * bA0[4]; u1[4] = wvb.x * bA1[4];
    u0[5] = wvb.y * bA0[5]; u1[5] = wvb.y * bA1[5];
    u0[6] = wvb.z * bA0[6]; u1[6] = wvb.z * bA1[6];
    u0[7] = wvb.w * bA0[7]; u1[7] = wvb.w * bA1[7];
#pragma unroll
    for (int n = 0; n < 2; ++n) {
      const float* qr = qb + n * (2 * HH);
      const float4 a0 = *reinterpret_cast<const float4*>(qr + h0);           // s_load
      const float4 a1 = *reinterpret_cast<const float4*>(qr + h0 + 4);
      const float4 v0 = *reinterpret_cast<const float4*>(qr + HH + h0);
      const float4 v1 = *reinterpret_cast<const float4*>(qr + HH + h0 + 4);
#pragma unroll
      for (int mm = 0; mm < 2; ++mm) {
        const float* bA = (mm == 0) ? bA0 : bA1;
        const float* uu = (mm == 0) ? u0 : u1;
        const float s0 = v0.x + uu[0], d0 = fmaf(a0.x, bA[0], 1.0f);
        const float s1 = v0.y + uu[1], d1 = fmaf(a0.y, bA[1], 1.0f);
        const float s2 = v0.z + uu[2], d2 = fmaf(a0.z, bA[2], 1.0f);
        const float s3 = v0.w + uu[3], d3 = fmaf(a0.w, bA[3], 1.0f);
        const float s4 = v1.x + uu[4], d4 = fmaf(a1.x, bA[4], 1.0f);
        const float s5 = v1.y + uu[5], d5 = fmaf(a1.y, bA[5], 1.0f);
        const float s6 = v1.z + uu[6], d6 = fmaf(a1.z, bA[6], 1.0f);
        const float s7 = v1.w + uu[7], d7 = fmaf(a1.w, bA[7], 1.0f);
        // pairwise rational tree: sum s_i/d_i -> t07/e07
        const float t01 = fmaf(s0, d1, s1 * d0), e01 = d0 * d1;
        const float t23 = fmaf(s2, d3, s3 * d2), e23 = d2 * d3;
        const float t45 = fmaf(s4, d5, s5 * d4), e45 = d4 * d5;
        const float t67 = fmaf(s6, d7, s7 * d6), e67 = d6 * d7;
        const float t03 = fmaf(t01, e23, t23 * e01), e03 = e01 * e23;
        const float t47 = fmaf(t45, e67, t67 * e45), e47 = e45 * e67;
        const float t07 = fmaf(t03, e47, t47 * e03), e07 = e03 * e47;
        if (n == 0 && mm == 0) { N00 = fmaf(N00, e07, t07 * D00); D00 *= e07; }
        if (n == 0 && mm == 1) { N01 = fmaf(N01, e07, t07 * D01); D01 *= e07; }
        if (n == 1 && mm == 0) { N10 = fmaf(N10, e07, t07 * D10); D10 *= e07; }
        if (n == 1 && mm == 1) { N11 = fmaf(N11, e07, t07 * D11); D11 *= e07; }
      }
    }
  }
  sp[g2 + 0][m0 + 0] = N00 * frcp(D00);
  sp[g2 + 0][m0 + 1] = N01 * frcp(D01);
  sp[g2 + 1][m0 + 0] = N10 * frcp(D10);
  sp[g2 + 1][m0 + 1] = N11 * frcp(D11);
  __syncthreads();

  // Phase 2: in-wave full-row softmax. wave w: row = w>>1, half = w&1.
  const int wave = t >> 6;
  const int lane = t & 63;
  const int row  = wave >> 1;
  const int hf   = wave & 1;
  float v[8];
  float mx = -1e30f;
#pragma unroll
  for (int i = 0; i < 8; ++i) {
    v[i] = sp[row][lane + 64 * i];     // full row, 8 vals/lane
    mx = fmaxf(mx, v[i]);
  }
#pragma unroll
  for (int off = 32; off > 0; off >>= 1) mx = fmaxf(mx, __shfl_xor(mx, off));
  float p[8];
  float sum = 0.f;
#pragma unroll
  for (int i = 0; i < 8; ++i) {
    p[i] = fexp2((v[i] - mx) * kLog2e);
    sum += p[i];
  }
#pragma unroll
  for (int off = 32; off > 0; off >>= 1) sum += __shfl_xor(sum, off);
  __syncthreads();                      // all row reads done before overwrite
#pragma unroll
  for (int i = 4 * hf; i < 4 * hf + 4; ++i) sp[row][lane + 64 * i] = p[i];
  if (hf == 0 && lane == 0) rsh[row] = frcp(sum);
  __syncthreads();

  // Phase 3: PV. mg = t>>7 (8 groups x 64 m), dp = (t&127)*2 (float2 d-pair).
  const float* __restrict__ vb = value + (size_t)b * SEQM * DV;
  const int dp = (t & 127) * 2;
  const int mg = t >> 7;
  float o[8][2];
#pragma unroll
  for (int n = 0; n < 8; ++n) { o[n][0] = 0.f; o[n][1] = 0.f; }
  const int mbeg = mg * 64;
  for (int mi = 0; mi < 64; mi += 4) {
    const int mq = mbeg + mi;
    const float2 w0 = *reinterpret_cast<const float2*>(vb + (size_t)(mq + 0) * DV + dp);
    const float2 w1 = *reinterpret_cast<const float2*>(vb + (size_t)(mq + 1) * DV + dp);
    const float2 w2 = *reinterpret_cast<const float2*>(vb + (size_t)(mq + 2) * DV + dp);
    const float2 w3 = *reinterpret_cast<const float2*>(vb + (size_t)(mq + 3) * DV + dp);
#pragma unroll
    for (int n = 0; n < 8; ++n) {
      const float4 p4 = *reinterpret_cast<const float4*>(&sp[n][mq]);  // broadcast
      o[n][0] = fmaf(p4.x, w0.x, fmaf(p4.y, w1.x, fmaf(p4.z, w2.x, fmaf(p4.w, w3.x, o[n][0]))));
      o[n][1] = fmaf(p4.x, w0.y, fmaf(p4.y, w1.y, fmaf(p4.z, w2.y, fmaf(p4.w, w3.y, o[n][1]))));
    }
  }
  if (mg >= 4) {
#pragma unroll
    for (int n = 0; n < 8; ++n)
      *reinterpret_cast<float2*>(&pvbuf[mg - 4][n][dp]) = make_float2(o[n][0], o[n][1]);
  }
  __syncthreads();
  if (mg < 4) {
#pragma unroll
    for (int n = 0; n < 8; ++n) {
      float2 prev = *reinterpret_cast<const float2*>(&pvbuf[mg][n][dp]);
      prev.x += o[n][0]; prev.y += o[n][1];
      *reinterpret_cast<float2*>(&pvbuf[mg][n][dp]) = prev;
    }
  }
  __syncthreads();

  // Final: n = t>>7, d = t&127 (and d+128): 2 outputs/thread.
  {
    const int n = t >> 7;
    const int d = t & 127;
    const float rsn = rsh[n];
    float accA = 0.f, accB = 0.f;
#pragma unroll
    for (int g = 0; g < 4; ++g) {
      accA += pvbuf[g][n][d];
      accB += pvbuf[g][n][d + 128];
    }
    const size_t ob = ((size_t)b * SEQN + n0 + n) * DV;
    out[ob + d]       = accA * rsn;
    out[ob + d + 128] = accB * rsn;
  }
}

extern "C" void kernel_launch(void* const* d_in, const int* in_sizes, int n_in,
                              void* d_out, int out_size, void* d_ws, size_t ws_size,
                              hipStream_t stream) {
  const float* query = (const float*)d_in[0];   // (4,512,256)
  const float* key   = (const float*)d_in[1];   // (4,512,256)
  const float* value = (const float*)d_in[2];   // (4,512,256)
  const float* W_q   = (const float*)d_in[3];   // (256,128)
  const float* W_k   = (const float*)d_in[4];   // (256,128)
  const float* W_v   = (const float*)d_in[5];   // (128,)
  float* out = (float*)d_out;                   // (4,512,256) f32

  // qt parks in d_out (2 MB): fused block (b,n0) reads only its OWN 8 q-rows
  // in phase 1 and overwrites exactly those rows at the end -> no hazard.
  float* qt  = (float*)d_out;                   // (2048, 256) [A | wv*A]
  float* ktT = (float*)d_ws;                    // [16][2048][8] chunk-tiled A, 2 MB

  proj_kernel<<<2 * (NB * SEQN) / 8, 512, 0, stream>>>(query, key, W_q, W_k, W_v, qt, ktT);
  fused_kernel<<<NB * (SEQN / 8), 1024, 0, stream>>>(qt, ktT, W_v, value, out);
}

// Round 18
// 45.644 us; speedup vs baseline: 1.2492x; 1.0136x over previous
//
#include <hip/hip_runtime.h>
#include <math.h>

#define NB   4
#define SEQN 512
#define SEQM 512
#define QS   256   // Q_SIZE == K_SIZE
#define HH   128   // H
#define DV   256   // D_V
#define BM   (NB * SEQM)   // 2048 global k rows

static constexpr float kPreScale = 2.8853900817779268f;  // 2*log2(e)
static constexpr float kLog2e    = 1.4426950408889634f;

#if __has_builtin(__builtin_amdgcn_exp2f)
__device__ __forceinline__ float fexp2(float x) { return __builtin_amdgcn_exp2f(x); }
#else
__device__ __forceinline__ float fexp2(float x) { return exp2f(x); }
#endif

#if __has_builtin(__builtin_amdgcn_rcpf)
__device__ __forceinline__ float frcp(float x) { return __builtin_amdgcn_rcpf(x); }
#else
__device__ __forceinline__ float frcp(float x) { return 1.0f / x; }
#endif

// Fused q/k projection + tanh precompute.
// grid: 512 blocks, 512 threads. Block: 8 rows x 128 cols; thread: 2 rows.
// Q output (CHUNK-PACKED): qc[row][c][0..7]=A(h=8c..8c+7), [c][8..15]=wv*A.
//   Each (row,chunk) is 64 B contiguous -> fused kernel reads it as ONE
//   s_load_dwordx16 (R18: collapses 10 SMEM instr/chunk to ~6 per 4 rows).
// K output (chunk-tiled, R17): ktT[c][global_row][j] = A for h = 8c+j.
__global__ __launch_bounds__(512) void proj_kernel(
    const float* __restrict__ query, const float* __restrict__ key,
    const float* __restrict__ Wq, const float* __restrict__ Wk,
    const float* __restrict__ wv,
    float* __restrict__ qc, float* __restrict__ ktT) {
  const int t = threadIdx.x;
  const int half = (NB * SEQN) / 8;            // 256
  const bool isK = blockIdx.x >= half;
  const int rb   = isK ? (blockIdx.x - half) : blockIdx.x;
  const float* __restrict__ in = isK ? key : query;
  const float* __restrict__ W  = isK ? Wk  : Wq;
  const int row0 = rb * 8;

  const int j  = t & 127;                                      // output column (h)
  const int r0 = __builtin_amdgcn_readfirstlane((t >> 7) * 2); // wave-uniform -> SGPR

  const float* __restrict__ x0p = in + (size_t)(row0 + r0 + 0) * QS;
  const float* __restrict__ x1p = in + (size_t)(row0 + r0 + 1) * QS;

  float a0 = 0.f, a1 = 0.f;
  for (int k0 = 0; k0 < QS; k0 += 4) {
    const float w0 = W[(k0 + 0) * HH + j];
    const float w1 = W[(k0 + 1) * HH + j];
    const float w2 = W[(k0 + 2) * HH + j];
    const float w3 = W[(k0 + 3) * HH + j];
    const float4 x0 = *reinterpret_cast<const float4*>(x0p + k0);  // s_load
    const float4 x1 = *reinterpret_cast<const float4*>(x1p + k0);
    a0 = fmaf(x0.x, w0, fmaf(x0.y, w1, fmaf(x0.z, w2, fmaf(x0.w, w3, a0))));
    a1 = fmaf(x1.x, w0, fmaf(x1.y, w1, fmaf(x1.z, w2, fmaf(x1.w, w3, a1))));
  }
  const float wvj = wv[j];
  float acc[2] = {a0, a1};
#pragma unroll
  for (int r = 0; r < 2; ++r) {
    const float e  = fexp2(acc[r] * kPreScale);          // e^{2x}
    const float rc = frcp(e + 1.0f);
    float A = fmaf(-2.0f, rc, 1.0f);                     // tanh(x)
    A = fminf(fmaxf(A, -0.99999988f), 0.99999988f);      // keep d = 1+AB > 0
    const int grow = row0 + r0 + r;
    if (isK) {
      ktT[(((size_t)(j >> 3) * BM) + grow) * 8 + (j & 7)] = A;
    } else {
      const size_t base = (size_t)grow * 256 + (size_t)(j >> 3) * 16 + (j & 7);
      qc[base]     = A;          // A slot
      qc[base + 8] = wvj * A;    // wv*A slot
    }
  }
}

// Fused scores + softmax + PV. R18: Tn=4 x Tm=2 register tile — joint cut of
// SMEM (dwordx16 q rows), VMEM, and unpack overhead per element; ILP over TLP.
// grid = NB * (SEQN/8) = 256 blocks, 512 threads (8 waves, 2/SIMD), 40 KB LDS.
// Thread: (ng = t>>8)*4 rows x m-pair (t&255)*2 -> 8 scores.
__global__ __launch_bounds__(512) void fused_kernel(
    const float* __restrict__ qc, const float* __restrict__ ktT,
    const float* __restrict__ wv, const float* __restrict__ value,
    float* __restrict__ out) {
  __shared__ float sp[8][SEQM];        // 16 KB: scores then unnormalized p
  __shared__ float pvbuf[3][8][DV];    // 24 KB: PV partial buffers
  __shared__ float rsh[8];             // 1/rowsum

  const int t  = threadIdx.x;            // 0..511
  const int b  = blockIdx.x >> 6;        // 4 batches x 64 tiles
  const int n0 = (blockIdx.x & 63) * 8;
  const int mslot = t & 255;
  const int m0 = 2 * mslot;
  // wave-uniform row-quad base (t>>8 flips at wave boundary 4)
  const int ng4 = __builtin_amdgcn_readfirstlane((t >> 8) * 4);

  const float* __restrict__ qb = qc + ((size_t)(b * SEQN + n0 + ng4)) * 256;
  const float* __restrict__ kbase = ktT + ((size_t)b * SEQM + m0) * 8;

  float N[4][2], D[4][2];
#pragma unroll
  for (int n = 0; n < 4; ++n) { N[n][0] = 0.f; N[n][1] = 0.f; D[n][0] = 1.f; D[n][1] = 1.f; }

  // k prefetch (chunk 0): 16 contiguous floats = {m0: h0-7, m1: h0-7}
  float4 f0 = *reinterpret_cast<const float4*>(kbase + 0);
  float4 f1 = *reinterpret_cast<const float4*>(kbase + 4);
  float4 f2 = *reinterpret_cast<const float4*>(kbase + 8);
  float4 f3 = *reinterpret_cast<const float4*>(kbase + 12);

  for (int c = 0; c < 16; ++c) {
    float bA0[8], bA1[8];
    bA0[0] = f0.x; bA0[1] = f0.y; bA0[2] = f0.z; bA0[3] = f0.w;
    bA0[4] = f1.x; bA0[5] = f1.y; bA0[6] = f1.z; bA0[7] = f1.w;
    bA1[0] = f2.x; bA1[1] = f2.y; bA1[2] = f2.z; bA1[3] = f2.w;
    bA1[4] = f3.x; bA1[5] = f3.y; bA1[6] = f3.z; bA1[7] = f3.w;
    if (c + 1 < 16) {
      const float* nb = kbase + (size_t)(c + 1) * BM * 8;
      f0 = *reinterpret_cast<const float4*>(nb + 0);
      f1 = *reinterpret_cast<const float4*>(nb + 4);
      f2 = *reinterpret_cast<const float4*>(nb + 8);
      f3 = *reinterpret_cast<const float4*>(nb + 12);
    }
    // wv chunk (wave-uniform s_loads)
    const float4 wva = *reinterpret_cast<const float4*>(wv + c * 8);
    const float4 wvb = *reinterpret_cast<const float4*>(wv + c * 8 + 4);
    float u0[8], u1[8];
    u0[0] = wva.x * bA0[0]; u1[0] = wva.x * bA1[0];
    u0[1] = wva.y * bA0[1]; u1[1] = wva.y * bA1[1];
    u0[2] = wva.z * bA0[2]; u1[2] = wva.z * bA1[2];
    u0[3] = wva.w * bA0[3]; u1[3] = wva.w * bA1[3];
    u0[4] = wvb.x * bA0[4]; u1[4] = wvb.x * bA1[4];
    u0[5] = wvb.y * bA0[5]; u1[5] = wvb.y * bA1[5];
    u0[6] = wvb.z * bA0[6]; u1[6] = wvb.z * bA1[6];
    u0[7] = wvb.w * bA0[7]; u1[7] = wvb.w * bA1[7];
#pragma unroll
    for (int n = 0; n < 4; ++n) {
      // one contiguous 64 B row-chunk -> s_load_dwordx16
      const float* qr = qb + (size_t)n * 256 + (size_t)c * 16;
      const float4 qa0 = *reinterpret_cast<const float4*>(qr + 0);   // A h0-3
      const float4 qa1 = *reinterpret_cast<const float4*>(qr + 4);   // A h4-7
      const float4 qv0 = *reinterpret_cast<const float4*>(qr + 8);   // wvA h0-3
      const float4 qv1 = *reinterpret_cast<const float4*>(qr + 12);  // wvA h4-7
#pragma unroll
      for (int mm = 0; mm < 2; ++mm) {
        const float* bA = (mm == 0) ? bA0 : bA1;
        const float* uu = (mm == 0) ? u0 : u1;
        const float s0 = qv0.x + uu[0], d0 = fmaf(qa0.x, bA[0], 1.0f);
        const float s1 = qv0.y + uu[1], d1 = fmaf(qa0.y, bA[1], 1.0f);
        const float s2 = qv0.z + uu[2], d2 = fmaf(qa0.z, bA[2], 1.0f);
        const float s3 = qv0.w + uu[3], d3 = fmaf(qa0.w, bA[3], 1.0f);
        const float s4 = qv1.x + uu[4], d4 = fmaf(qa1.x, bA[4], 1.0f);
        const float s5 = qv1.y + uu[5], d5 = fmaf(qa1.y, bA[5], 1.0f);
        const float s6 = qv1.z + uu[6], d6 = fmaf(qa1.z, bA[6], 1.0f);
        const float s7 = qv1.w + uu[7], d7 = fmaf(qa1.w, bA[7], 1.0f);
        // pairwise rational tree: sum s_i/d_i -> t07/e07
        const float t01 = fmaf(s0, d1, s1 * d0), e01 = d0 * d1;
        const float t23 = fmaf(s2, d3, s3 * d2), e23 = d2 * d3;
        const float t45 = fmaf(s4, d5, s5 * d4), e45 = d4 * d5;
        const float t67 = fmaf(s6, d7, s7 * d6), e67 = d6 * d7;
        const float t03 = fmaf(t01, e23, t23 * e01), e03 = e01 * e23;
        const float t47 = fmaf(t45, e67, t67 * e45), e47 = e45 * e67;
        const float t07 = fmaf(t03, e47, t47 * e03), e07 = e03 * e47;
        N[n][mm] = fmaf(N[n][mm], e07, t07 * D[n][mm]);
        D[n][mm] *= e07;
      }
    }
  }
#pragma unroll
  for (int n = 0; n < 4; ++n) {
    sp[ng4 + n][m0 + 0] = N[n][0] * frcp(D[n][0]);
    sp[ng4 + n][m0 + 1] = N[n][1] * frcp(D[n][1]);
  }
  __syncthreads();

  // Phase 2: softmax, one full row per wave (8 waves, 8 rows).
  const int wave = t >> 6;
  const int lane = t & 63;
  {
    float v[8];
    float mx = -1e30f;
#pragma unroll
    for (int i = 0; i < 8; ++i) {
      v[i] = sp[wave][lane + 64 * i];
      mx = fmaxf(mx, v[i]);
    }
#pragma unroll
    for (int off = 32; off > 0; off >>= 1) mx = fmaxf(mx, __shfl_xor(mx, off));
    float sum = 0.f;
#pragma unroll
    for (int i = 0; i < 8; ++i) {
      const float p = fexp2((v[i] - mx) * kLog2e);
      sum += p;
      sp[wave][lane + 64 * i] = p;     // same wave read it fully above
    }
#pragma unroll
    for (int off = 32; off > 0; off >>= 1) sum += __shfl_xor(sum, off);
    if (lane == 0) rsh[wave] = frcp(sum);
  }
  __syncthreads();

  // Phase 3: PV. mg = t>>7 (4 groups x 128 m), dp = (t&127)*2 (float2 d-pair).
  const float* __restrict__ vb = value + (size_t)b * SEQM * DV;
  const int dp = (t & 127) * 2;
  const int mg = t >> 7;
  float o[8][2];
#pragma unroll
  for (int n = 0; n < 8; ++n) { o[n][0] = 0.f; o[n][1] = 0.f; }
  const int mbeg = mg * 128;
  for (int mi = 0; mi < 128; mi += 4) {
    const int mq = mbeg + mi;
    const float2 w0 = *reinterpret_cast<const float2*>(vb + (size_t)(mq + 0) * DV + dp);
    const float2 w1 = *reinterpret_cast<const float2*>(vb + (size_t)(mq + 1) * DV + dp);
    const float2 w2 = *reinterpret_cast<const float2*>(vb + (size_t)(mq + 2) * DV + dp);
    const float2 w3 = *reinterpret_cast<const float2*>(vb + (size_t)(mq + 3) * DV + dp);
#pragma unroll
    for (int n = 0; n < 8; ++n) {
      const float4 p4 = *reinterpret_cast<const float4*>(&sp[n][mq]);  // broadcast
      o[n][0] = fmaf(p4.x, w0.x, fmaf(p4.y, w1.x, fmaf(p4.z, w2.x, fmaf(p4.w, w3.x, o[n][0]))));
      o[n][1] = fmaf(p4.x, w0.y, fmaf(p4.y, w1.y, fmaf(p4.z, w2.y, fmaf(p4.w, w3.y, o[n][1]))));
    }
  }
  if (mg >= 1) {
#pragma unroll
    for (int n = 0; n < 8; ++n)
      *reinterpret_cast<float2*>(&pvbuf[mg - 1][n][dp]) = make_float2(o[n][0], o[n][1]);
  }
  __syncthreads();
  if (mg == 0) {
#pragma unroll
    for (int n = 0; n < 8; ++n) {
      const float rsn = rsh[n];
      float accA = o[n][0], accB = o[n][1];
#pragma unroll
      for (int g = 0; g < 3; ++g) {
        accA += pvbuf[g][n][dp];
        accB += pvbuf[g][n][dp + 1];
      }
      const size_t ob = ((size_t)b * SEQN + n0 + n) * DV;
      out[ob + dp]     = accA * rsn;
      out[ob + dp + 1] = accB * rsn;
    }
  }
}

extern "C" void kernel_launch(void* const* d_in, const int* in_sizes, int n_in,
                              void* d_out, int out_size, void* d_ws, size_t ws_size,
                              hipStream_t stream) {
  const float* query = (const float*)d_in[0];   // (4,512,256)
  const float* key   = (const float*)d_in[1];   // (4,512,256)
  const float* value = (const float*)d_in[2];   // (4,512,256)
  const float* W_q   = (const float*)d_in[3];   // (256,128)
  const float* W_k   = (const float*)d_in[4];   // (256,128)
  const float* W_v   = (const float*)d_in[5];   // (128,)
  float* out = (float*)d_out;                   // (4,512,256) f32

  // qc parks in d_out (2 MB): fused block (b,n0) reads only its OWN 8 q-rows
  // in phase 1 and overwrites exactly those rows at the end -> no hazard.
  float* qc  = (float*)d_out;                   // [2048][16][16] chunk-packed q
  float* ktT = (float*)d_ws;                    // [16][2048][8] chunk-tiled A, 1 MB

  proj_kernel<<<2 * (NB * SEQN) / 8, 512, 0, stream>>>(query, key, W_q, W_k, W_v, qc, ktT);
  fused_kernel<<<NB * (SEQN / 8), 512, 0, stream>>>(qc, ktT, W_v, value, out);
}